// Round 12
// baseline (621.586 us; speedup 1.0000x reference)
//
#include <hip/hip_runtime.h>
#include <math.h>

#define D_DIM 128
#define TWO_D 256
#define HC    512
#define NH    4
#define RNUM  8
#define BM    128

#define M_CNT  0
#define M_OFF  8
#define M_BLK  17
#define M_CUR  26
#define M_CUR2 34

typedef __attribute__((ext_vector_type(8))) short v8s;
typedef __attribute__((ext_vector_type(4))) float v4f;
typedef __attribute__((ext_vector_type(8))) unsigned short us8;

#define MFMA(a,b,c) __builtin_amdgcn_mfma_f32_16x16x32_bf16((a),(b),(c),0,0,0)

__device__ __forceinline__ float bf2f(unsigned short v){
    return __uint_as_float(((unsigned)v) << 16);
}
__device__ __forceinline__ unsigned short f2bf(float f){
    unsigned u = __float_as_uint(f);
    u += 0x7fffu + ((u >> 16) & 1u);
    return (unsigned short)(u >> 16);
}

// ---- LDS swizzled tile: slot cp of row r holds global chunk cp^(r&7) ----
__device__ __forceinline__ v8s frag_ld(const unsigned short* buf, int r, int chunk){
    return *(const v8s*)(buf + r * 64 + ((chunk ^ (r & 7)) << 3));
}
// ---- B-fragment direct from global: 8 contiguous k-elems, 16B aligned ----
__device__ __forceinline__ v8s frag_gl(const unsigned short* gbase, long row, long stride, int k0){
    return *(const v8s*)(gbase + row * stride + k0);
}

// ---- async staging: global_load_lds width=16, linear LDS dest + swizzled SOURCE (rule #21) ----
template<typename RowFn>
__device__ __forceinline__ void stage_gl(unsigned short* lds, RowFn rowp, int col0, int tid){
    const int lane = tid & 63;
    const int w = tid >> 6;
    #pragma unroll
    for (int i = 0; i < 4; i++){
        const int k = w * 4 + i;
        const int o = k * 1024 + lane * 16;     // byte offset within tile
        const int rr = o >> 7;                  // row (128 B/row)
        const int cp = (o & 127) >> 4;          // LDS chunk slot
        const int cg = cp ^ (rr & 7);           // global chunk (source pre-swizzle)
        const unsigned short* src = rowp(rr) + col0 + cg * 8;
        unsigned short* dst = lds + k * 512;    // wave-uniform base (elems)
        __builtin_amdgcn_global_load_lds((const __attribute__((address_space(1))) void*)src,
                                         (__attribute__((address_space(3))) void*)dst,
                                         16, 0, 0);
    }
}

// ---------------- prep: bf16 conversions + transposes + counter init (merged) ----------------
__global__ void k_prep(const float* __restrict__ embs, const float* __restrict__ rel,
                       const float* __restrict__ W_e, const float* __restrict__ W_l,
                       unsigned short* __restrict__ embs_bf, unsigned short* __restrict__ rel_t,
                       unsigned short* __restrict__ W_e_t, unsigned short* __restrict__ W_l_t,
                       int* __restrict__ meta, int* __restrict__ tcnt, int* __restrict__ tcur,
                       int N){
    const long T0 = (long)N * D_DIM;
    const long T1 = T0 + (long)RNUM * D_DIM * TWO_D;
    const long T2 = T1 + (long)HC * D_DIM;
    const long T3 = T2 + (long)HC * D_DIM;
    const long stride = (long)gridDim.x * blockDim.x;
    const long gid = (long)blockIdx.x * blockDim.x + threadIdx.x;

    for (long i = gid; i < N; i += stride){ tcnt[i] = 0; tcur[i] = 0; }
    if (gid < RNUM) meta[M_CNT + gid] = 0;

    const long NE8 = T0 / 8;
    for (long i = gid; i < NE8; i += stride){
        const float4* p = (const float4*)(embs + i * 8);
        float4 a = p[0], b = p[1];
        us8 o;
        o[0]=f2bf(a.x); o[1]=f2bf(a.y); o[2]=f2bf(a.z); o[3]=f2bf(a.w);
        o[4]=f2bf(b.x); o[5]=f2bf(b.y); o[6]=f2bf(b.z); o[7]=f2bf(b.w);
        *(us8*)(embs_bf + i * 8) = o;
    }
    for (long i = T0 + gid; i < T3; i += stride){
        if (i < T1){
            long j = i - T0;
            int r = (int)(j >> 15);
            int rem = (int)(j & 32767);
            int n = rem >> 8, k = rem & 255;
            rel_t[j] = f2bf(rel[(long)r * 32768 + (long)k * D_DIM + n]);
        } else if (i < T2){
            long j = i - T1;
            int n = (int)(j >> 7), k = (int)(j & 127);
            W_e_t[j] = f2bf(W_e[(long)k * HC + n]);
        } else {
            long j = i - T2;
            int n = (int)(j >> 7), k = (int)(j & 127);
            W_l_t[j] = f2bf(W_l[(long)k * HC + n]);
        }
    }
}

// ---------------- counting: relation histogram + per-target degree (merged) ----------------
__global__ void k_count(const int* __restrict__ etype, const int* __restrict__ trg,
                        int* __restrict__ meta, int* __restrict__ tcnt, int E){
    __shared__ int h[RNUM];
    int tid = threadIdx.x;
    if (tid < RNUM) h[tid] = 0;
    __syncthreads();
    int e = blockIdx.x * 256 + tid;
    if (e < E){
        atomicAdd(&h[etype[e]], 1);
        atomicAdd(&tcnt[trg[e]], 1);
    }
    __syncthreads();
    if (tid < RNUM) atomicAdd(&meta[M_CNT + tid], h[tid]);
}

// ---------------- scatter: build CSR-ordered srcp/trgp/etypep ----------------
__global__ void k_scatter2(const int* __restrict__ etype, const int* __restrict__ trg,
                           const int* __restrict__ src,
                           const int* __restrict__ rowptr, int* __restrict__ tcur,
                           int* __restrict__ srcp, int* __restrict__ trgp,
                           int* __restrict__ etypep, int E){
    int e = blockIdx.x * 256 + threadIdx.x;
    if (e < E){
        int t = trg[e];
        int pos = rowptr[t] + atomicAdd(&tcur[t], 1);
        srcp[pos] = src[e];
        trgp[pos] = t;
        etypep[pos] = etype[e];
    }
}

// ---------------- rscatter: bucket CSR POSITIONS by relation (ascending within relation) ----------------
__global__ void k_rscatter(const int* __restrict__ etypep, int* __restrict__ meta,
                           int* __restrict__ perm, int E){
    __shared__ int lcnt[RNUM], lbase[RNUM];
    int tid = threadIdx.x;
    if (tid < RNUM) lcnt[tid] = 0;
    __syncthreads();
    int p = blockIdx.x * 256 + tid;
    int r = 0, rank = 0;
    if (p < E){ r = etypep[p]; rank = atomicAdd(&lcnt[r], 1); }
    __syncthreads();
    if (tid < RNUM) lbase[tid] = atomicAdd(&meta[M_CUR2 + tid], lcnt[tid]);
    __syncthreads();
    if (p < E) perm[meta[M_OFF + r] + lbase[r] + rank] = p;
}

// =================== MFMA GEMM kernels ===================
#define ZP 132

// ---------------- fat kernel: k_x blocks + one tscan block (independent work, one launch) ----
// B-operand (W_l_t) read directly from global per-fragment (L2-resident weight).
__global__ __launch_bounds__(256, 4) void k_x_tscan(
    const unsigned short* __restrict__ embs_bf, const unsigned short* __restrict__ W_l_t,
    const float* __restrict__ b_l, unsigned short* __restrict__ x_bf, int N,
    const int* __restrict__ tcnt, int* __restrict__ rowptr, int* __restrict__ meta)
{
    __shared__ __align__(16) char smem[64 * ZP * 4];

    // ---- last block: 256-thread scan (runs concurrently with the GEMM blocks) ----
    if (blockIdx.x == gridDim.x - 1){
        int* part = (int*)smem;
        const int T = 256;
        int tid = threadIdx.x;
        if (tid == 0){
            int offv = 0, blkv = 0;
            meta[M_OFF] = 0; meta[M_BLK] = 0;
            for (int r2 = 0; r2 < RNUM; r2++){
                int c = meta[M_CNT + r2];
                offv += c; blkv += (c + BM - 1) / BM;
                meta[M_OFF + r2 + 1] = offv;
                meta[M_BLK + r2 + 1] = blkv;
                meta[M_CUR + r2] = 0;
                meta[M_CUR2 + r2] = 0;
            }
        }
        int chunk = (N + T - 1) / T;
        int lo = tid * chunk, hi = min(lo + chunk, N);
        int s = 0;
        for (int i = lo; i < hi; i++) s += tcnt[i];
        part[tid] = s;
        __syncthreads();
        for (int off = 1; off < T; off <<= 1){
            int v = (tid >= off) ? part[tid - off] : 0;
            __syncthreads();
            part[tid] += v;
            __syncthreads();
        }
        int run = (tid == 0) ? 0 : part[tid - 1];
        for (int i = lo; i < hi; i++){ rowptr[i] = run; run += tcnt[i]; }
        if (tid == T - 1) rowptr[N] = part[T - 1];
        return;
    }

    unsigned short* Ab = (unsigned short*)smem;
    float* zb = (float*)smem;

    const int xb = (N + BM - 1) / BM;
    const int bid = blockIdx.x;
    const int cg = bid / xb;
    const int n0 = (bid - cg * xb) * BM;
    const int tid = threadIdx.x;
    const int cnt = min(BM, N - n0);
    const int w = tid >> 6, lane = tid & 63, m = lane & 15, q = lane >> 4;

    v4f acc[2][8];
    #pragma unroll
    for (int i = 0; i < 2; i++)
        #pragma unroll
        for (int j = 0; j < 8; j++) acc[i][j] = 0.f;

    #pragma unroll
    for (int ch = 0; ch < 2; ch++){
        __syncthreads();
        stage_gl(Ab, [&](int rr){ return embs_bf + (long)min(n0 + rr, N - 1) * D_DIM; },
                 ch * 64, tid);
        __syncthreads();
        #pragma unroll
        for (int ks = 0; ks < 2; ks++){
            const int k0 = ch * 64 + (ks * 4 + q) * 8;
            v8s af[2], bf[8];
            #pragma unroll
            for (int rt = 0; rt < 2; rt++) af[rt] = frag_ld(Ab, w*32 + rt*16 + m, ks*4 + q);
            #pragma unroll
            for (int ct = 0; ct < 8; ct++)
                bf[ct] = frag_gl(W_l_t, (long)(cg * BM + ct*16 + m), D_DIM, k0);
            #pragma unroll
            for (int rt = 0; rt < 2; rt++)
                #pragma unroll
                for (int ct = 0; ct < 8; ct++)
                    acc[rt][ct] = MFMA(af[rt], bf[ct], acc[rt][ct]);
        }
    }
    __syncthreads();

    for (int pp = 0; pp < 2; pp++){
        if ((w >> 1) == pp){
            int wr = (w & 1) * 32;
            #pragma unroll
            for (int rt = 0; rt < 2; rt++)
                #pragma unroll
                for (int ct = 0; ct < 8; ct++)
                    #pragma unroll
                    for (int g = 0; g < 4; g++)
                        zb[(wr + rt*16 + q*4 + g) * ZP + ct*16 + m] = acc[rt][ct][g];
        }
        __syncthreads();
        int rl = tid >> 2, pq = tid & 3;
        int row = pp * 64 + rl;
        if (row < cnt){
            const float* zp = zb + rl * ZP + pq * 32;
            const float* blp = b_l + cg * BM + pq * 32;
            long dst = (long)(n0 + row) * HC + cg * BM + pq * 32;
            #pragma unroll
            for (int g2 = 0; g2 < 4; g2++){
                us8 o;
                #pragma unroll
                for (int j = 0; j < 8; j++)
                    o[j] = f2bf(zp[g2*8 + j] + blp[g2*8 + j]);
                *(us8*)&x_bf[dst + g2*8] = o;
            }
        }
        __syncthreads();
    }
}

// ---------------- k_attr: relation-grouped over CSR positions; B (rel_t) direct from global ----
__global__ __launch_bounds__(256, 4) void k_attr_mfma(
    const unsigned short* __restrict__ embs_bf, const int* __restrict__ srcp,
    const int* __restrict__ trgp, const unsigned short* __restrict__ rel_t,
    const int* __restrict__ perm, const int* __restrict__ meta,
    unsigned short* __restrict__ edge_attrp)
{
    __shared__ __align__(16) char smem[64 * ZP * 4];
    unsigned short* Ab = (unsigned short*)smem;
    float* zb = (float*)smem;
    __shared__ int s_ep[BM], s_s[BM], s_t[BM];
    __shared__ int s_meta[3];

    const int tid = threadIdx.x;
    const int b = blockIdx.x;
    if (tid == 0){
        int nblk = meta[M_BLK + RNUM];
        if (b >= nblk){ s_meta[0] = -1; }
        else {
            int r = 0;
            while (b >= meta[M_BLK + r + 1]) r++;
            int chunk = b - meta[M_BLK + r];
            int base = meta[M_OFF + r] + chunk * BM;
            s_meta[0] = r; s_meta[1] = base;
            s_meta[2] = min(BM, meta[M_OFF + r + 1] - base);
        }
    }
    __syncthreads();
    const int r = s_meta[0];
    if (r < 0) return;
    const int base = s_meta[1], cnt = s_meta[2];
    if (tid < BM){
        int pos = perm[base + min(tid, cnt - 1)];
        s_ep[tid] = pos; s_s[tid] = srcp[pos]; s_t[tid] = trgp[pos];
    }
    const int w = tid >> 6, lane = tid & 63, m = lane & 15, q = lane >> 4;

    v4f acc[2][8];
    #pragma unroll
    for (int i = 0; i < 2; i++)
        #pragma unroll
        for (int j = 0; j < 8; j++) acc[i][j] = 0.f;

    __syncthreads();

    #pragma unroll
    for (int ch = 0; ch < 4; ch++){
        __syncthreads();
        stage_gl(Ab, [&](int rr){ int node = (ch < 2) ? s_s[rr] : s_t[rr];
                                  return embs_bf + (long)node * D_DIM; },
                 (ch & 1) * 64, tid);
        __syncthreads();
        #pragma unroll
        for (int ks = 0; ks < 2; ks++){
            const int k0 = ch * 64 + (ks * 4 + q) * 8;
            v8s af[2], bf[8];
            #pragma unroll
            for (int rt = 0; rt < 2; rt++) af[rt] = frag_ld(Ab, w*32 + rt*16 + m, ks*4 + q);
            #pragma unroll
            for (int ct = 0; ct < 8; ct++)
                bf[ct] = frag_gl(rel_t, (long)r * BM + ct*16 + m, TWO_D, k0);
            #pragma unroll
            for (int rt = 0; rt < 2; rt++)
                #pragma unroll
                for (int ct = 0; ct < 8; ct++)
                    acc[rt][ct] = MFMA(af[rt], bf[ct], acc[rt][ct]);
        }
    }
    __syncthreads();

    for (int pp = 0; pp < 2; pp++){
        if ((w >> 1) == pp){
            int wr = (w & 1) * 32;
            #pragma unroll
            for (int rt = 0; rt < 2; rt++)
                #pragma unroll
                for (int ct = 0; ct < 8; ct++)
                    #pragma unroll
                    for (int g = 0; g < 4; g++)
                        zb[(wr + rt*16 + q*4 + g) * ZP + ct*16 + m] = acc[rt][ct][g];
        }
        __syncthreads();
        int rl = tid >> 2, pq = tid & 3;
        int row = pp * 64 + rl;
        if (row < cnt){
            const float* zp = zb + rl * ZP + pq * 32;
            long dst = (long)s_ep[row] * D_DIM + pq * 32;
            #pragma unroll
            for (int g2 = 0; g2 < 4; g2++){
                us8 o;
                #pragma unroll
                for (int j = 0; j < 8; j++){
                    float v = zp[g2*8 + j];
                    v = 0.5f * v * (1.f + erff(v * 0.70710678118654752f));
                    o[j] = f2bf(v);
                }
                *(us8*)&edge_attrp[dst + g2*8] = o;
            }
        }
        __syncthreads();
    }
}

// ---------------- k_logits: XCD head-sibling dispatch; B (W_e_t) direct from global ----------------
__global__ __launch_bounds__(256, 4) void k_logits_mfma(
    const unsigned short* __restrict__ edge_attrp, const unsigned short* __restrict__ W_e_t,
    const float* __restrict__ att, const unsigned short* __restrict__ x_bf,
    const int* __restrict__ srcp, const int* __restrict__ trgp,
    float* __restrict__ logitsp, int E)
{
    __shared__ __align__(16) char smem[64 * ZP * 4];
    unsigned short* Ab = (unsigned short*)smem;
    float* zb = (float*)smem;
    __shared__ int s_s[BM], s_t[BM];

    const int tid = threadIdx.x;
    const int bid = blockIdx.x;
    const int g = bid >> 5, r5 = bid & 31;
    const int tile = g * 8 + (r5 & 7);
    const int h = r5 >> 3;
    const int lbv = (E + BM - 1) / BM;
    if (tile >= lbv) return;
    const int e0 = tile * BM;
    const int cnt = min(BM, E - e0);
    if (tid < BM){
        int e = e0 + min(tid, cnt - 1);
        s_s[tid] = srcp[e]; s_t[tid] = trgp[e];
    }
    const int w = tid >> 6, lane = tid & 63, m = lane & 15, q = lane >> 4;

    v4f acc[2][8];
    #pragma unroll
    for (int i = 0; i < 2; i++)
        #pragma unroll
        for (int j = 0; j < 8; j++) acc[i][j] = 0.f;

    #pragma unroll
    for (int ch = 0; ch < 2; ch++){
        __syncthreads();
        stage_gl(Ab, [&](int rr){ return edge_attrp + (long)(e0 + min(rr, cnt - 1)) * D_DIM; },
                 ch * 64, tid);
        __syncthreads();
        #pragma unroll
        for (int ks = 0; ks < 2; ks++){
            const int k0 = ch * 64 + (ks * 4 + q) * 8;
            v8s af[2], bf[8];
            #pragma unroll
            for (int rt = 0; rt < 2; rt++) af[rt] = frag_ld(Ab, w*32 + rt*16 + m, ks*4 + q);
            #pragma unroll
            for (int ct = 0; ct < 8; ct++)
                bf[ct] = frag_gl(W_e_t, (long)(h * BM + ct*16 + m), D_DIM, k0);
            #pragma unroll
            for (int rt = 0; rt < 2; rt++)
                #pragma unroll
                for (int ct = 0; ct < 8; ct++)
                    acc[rt][ct] = MFMA(af[rt], bf[ct], acc[rt][ct]);
        }
    }
    __syncthreads();

    for (int pp = 0; pp < 2; pp++){
        if ((w >> 1) == pp){
            int wr = (w & 1) * 32;
            #pragma unroll
            for (int rt = 0; rt < 2; rt++)
                #pragma unroll
                for (int ct = 0; ct < 8; ct++)
                    #pragma unroll
                    for (int g2 = 0; g2 < 4; g2++)
                        zb[(wr + rt*16 + q*4 + g2) * ZP + ct*16 + m] = acc[rt][ct][g2];
        }
        __syncthreads();
        int rl = tid >> 2, pq = tid & 3;
        int row = pp * 64 + rl;
        float part = 0.f;
        if (row < cnt){
            int s = s_s[row], t = s_t[row];
            const float* zp = zb + rl * ZP + pq * 32;
            const unsigned short* xip = x_bf + (long)t * HC + h * BM + pq * 32;
            const unsigned short* xjp = x_bf + (long)s * HC + h * BM + pq * 32;
            const float* ap = att + h * BM + pq * 32;
            #pragma unroll
            for (int g2 = 0; g2 < 4; g2++){
                us8 xi = *(const us8*)(xip + g2*8);
                us8 xj = *(const us8*)(xjp + g2*8);
                #pragma unroll
                for (int j = 0; j < 8; j++){
                    float z = zp[g2*8 + j] + bf2f(xi[j]) + bf2f(xj[j]);
                    z = (z > 0.f) ? z : 0.2f * z;
                    part += z * ap[g2*8 + j];
                }
            }
        }
        part += __shfl_xor(part, 1, 64);
        part += __shfl_xor(part, 2, 64);
        if ((tid & 3) == 0 && row < cnt)
            logitsp[(long)(e0 + row) * NH + h] = part;
        __syncthreads();
    }
}

// ---------------- CSR aggregation: contiguous logits/src, 2-pass softmax ----------------
__global__ __launch_bounds__(256) void k_agg_csr(
    const float* __restrict__ logitsp, const int* __restrict__ rowptr,
    const int* __restrict__ srcp,
    const unsigned short* __restrict__ x_bf, const float* __restrict__ bias,
    float* __restrict__ out, int N)
{
    int t = blockIdx.x * 4 + (threadIdx.x >> 6);
    if (t >= N) return;
    int lane = threadIdx.x & 63;
    int c0 = lane * 8;
    int h = lane >> 4;                   // head for my 8 cols
    int lo = rowptr[t], hi = rowptr[t + 1];

    float acc[8];
    #pragma unroll
    for (int j = 0; j < 8; j++) acc[j] = 0.f;

    if (lo < hi){
        float mx = -3.0e38f;
        for (int i = lo; i < hi; i++)
            mx = fmaxf(mx, logitsp[(long)i * NH + h]);
        float ssum = 0.f;
        for (int i = lo; i < hi; i++){
            float ew = expf(logitsp[(long)i * NH + h] - mx);
            ssum += ew;
            us8 xv = *(const us8*)&x_bf[(long)srcp[i] * HC + c0];
            #pragma unroll
            for (int j = 0; j < 8; j++) acc[j] += ew * bf2f(xv[j]);
        }
        float inv = 1.f / fmaxf(ssum, 1e-16f);
        #pragma unroll
        for (int j = 0; j < 8; j++) acc[j] *= inv;
    }
    long dst = (long)t * HC + c0;
    *(float4*)&out[dst]     = make_float4(acc[0] + bias[c0+0], acc[1] + bias[c0+1],
                                          acc[2] + bias[c0+2], acc[3] + bias[c0+3]);
    *(float4*)&out[dst + 4] = make_float4(acc[4] + bias[c0+4], acc[5] + bias[c0+5],
                                          acc[6] + bias[c0+6], acc[7] + bias[c0+7]);
}

extern "C" void kernel_launch(void* const* d_in, const int* in_sizes, int n_in,
                              void* d_out, int out_size, void* d_ws, size_t ws_size,
                              hipStream_t stream) {
    const float* embs       = (const float*)d_in[0];
    const int*   edge_index = (const int*)  d_in[1];
    const int*   etype      = (const int*)  d_in[2];
    const float* rel        = (const float*)d_in[3];
    const float* W_l        = (const float*)d_in[4];
    const float* b_l        = (const float*)d_in[5];
    const float* W_e        = (const float*)d_in[6];
    const float* att        = (const float*)d_in[7];
    const float* bias       = (const float*)d_in[8];

    const int N = in_sizes[0] / D_DIM;
    const int E = in_sizes[1] / 2;
    const int* src = edge_index;
    const int* trg = edge_index + E;

    char* ws = (char*)d_ws;
    size_t off = 0;
    unsigned short* x_bf = (unsigned short*)(ws + off);      off += (size_t)N * HC * 2;
    unsigned short* embs_bf = (unsigned short*)(ws + off);   off += (size_t)N * D_DIM * 2;
    unsigned short* edge_attrp = (unsigned short*)(ws + off); off += (size_t)E * D_DIM * 2;
    unsigned short* rel_t = (unsigned short*)(ws + off);     off += (size_t)RNUM * D_DIM * TWO_D * 2;
    unsigned short* W_e_t = (unsigned short*)(ws + off);     off += (size_t)HC * D_DIM * 2;
    unsigned short* W_l_t = (unsigned short*)(ws + off);     off += (size_t)HC * D_DIM * 2;
    float* logitsp = (float*)(ws + off);                     off += (size_t)E * NH * 4;
    int* perm = (int*)(ws + off);                            off += (size_t)E * 4;
    int* meta = (int*)(ws + off);                            off += 64 * 4;
    int* tcnt = (int*)(ws + off);                            off += (size_t)N * 4;
    int* tcur = (int*)(ws + off);                            off += (size_t)N * 4;
    int* rowptr = (int*)(ws + off);                          off += (size_t)(N + 1) * 4;
    int* etypep = (int*)(ws + off);                          off += (size_t)E * 4;
    int* srcp = (int*)(ws + off);                            off += (size_t)E * 4;
    int* trgp = (int*)(ws + off);                            off += (size_t)E * 4;

    float* out = (float*)d_out;

    const int eb = (E + 255) / 256;
    const int ab = (E + BM - 1) / BM + RNUM;
    const int lb = (E + BM - 1) / BM;
    const int xb = (N + BM - 1) / BM;
    const int lgrid = ((lb + 7) / 8) * 32;   // tile-octet groups x 4 heads

    k_prep<<<2048, 256, 0, stream>>>(embs, rel, W_e, W_l, embs_bf, rel_t, W_e_t, W_l_t,
                                     meta, tcnt, tcur, N);
    k_count<<<eb, 256, 0, stream>>>(etype, trg, meta, tcnt, E);
    k_x_tscan<<<xb * NH + 1, 256, 0, stream>>>(embs_bf, W_l_t, b_l, x_bf, N,
                                               tcnt, rowptr, meta);
    k_scatter2<<<eb, 256, 0, stream>>>(etype, trg, src, rowptr, tcur, srcp, trgp, etypep, E);
    k_rscatter<<<eb, 256, 0, stream>>>(etypep, meta, perm, E);
    k_attr_mfma<<<ab, 256, 0, stream>>>(embs_bf, srcp, trgp, rel_t, perm, meta, edge_attrp);
    k_logits_mfma<<<lgrid, 256, 0, stream>>>(edge_attrp, W_e_t, att, x_bf, srcp, trgp,
                                             logitsp, E);
    k_agg_csr<<<(N + 3) / 4, 256, 0, stream>>>(logitsp, rowptr, srcp, x_bf, bias, out, N);
}

// Round 13
// 468.578 us; speedup vs baseline: 1.3265x; 1.3265x over previous
//
#include <hip/hip_runtime.h>
#include <math.h>

#define D_DIM 128
#define TWO_D 256
#define HC    512
#define NH    4
#define RNUM  8
#define BM    128

#define M_CNT  0
#define M_OFF  8
#define M_BLK  17
#define M_CUR  26
#define M_CUR2 34

typedef __attribute__((ext_vector_type(8))) short v8s;
typedef __attribute__((ext_vector_type(4))) float v4f;
typedef __attribute__((ext_vector_type(8))) unsigned short us8;

#define MFMA(a,b,c) __builtin_amdgcn_mfma_f32_16x16x32_bf16((a),(b),(c),0,0,0)

__device__ __forceinline__ float bf2f(unsigned short v){
    return __uint_as_float(((unsigned)v) << 16);
}
__device__ __forceinline__ unsigned short f2bf(float f){
    unsigned u = __float_as_uint(f);
    u += 0x7fffu + ((u >> 16) & 1u);
    return (unsigned short)(u >> 16);
}

// ---- LDS swizzled tile: slot cp of row r holds global chunk cp^(r&7) ----
__device__ __forceinline__ v8s frag_ld(const unsigned short* buf, int r, int chunk){
    return *(const v8s*)(buf + r * 64 + ((chunk ^ (r & 7)) << 3));
}

// ---- async staging: global_load_lds width=16, linear LDS dest + swizzled SOURCE (rule #21) ----
template<typename RowFn>
__device__ __forceinline__ void stage_gl(unsigned short* lds, RowFn rowp, int col0, int tid){
    const int lane = tid & 63;
    const int w = tid >> 6;
    #pragma unroll
    for (int i = 0; i < 4; i++){
        const int k = w * 4 + i;
        const int o = k * 1024 + lane * 16;     // byte offset within tile
        const int rr = o >> 7;                  // row (128 B/row)
        const int cp = (o & 127) >> 4;          // LDS chunk slot
        const int cg = cp ^ (rr & 7);           // global chunk (source pre-swizzle)
        const unsigned short* src = rowp(rr) + col0 + cg * 8;
        unsigned short* dst = lds + k * 512;    // wave-uniform base (elems)
        __builtin_amdgcn_global_load_lds((const __attribute__((address_space(1))) void*)src,
                                         (__attribute__((address_space(3))) void*)dst,
                                         16, 0, 0);
    }
}

// ---------------- prep: bf16 conversions + transposes + counter init (merged) ----------------
__global__ void k_prep(const float* __restrict__ embs, const float* __restrict__ rel,
                       const float* __restrict__ W_e, const float* __restrict__ W_l,
                       unsigned short* __restrict__ embs_bf, unsigned short* __restrict__ rel_t,
                       unsigned short* __restrict__ W_e_t, unsigned short* __restrict__ W_l_t,
                       int* __restrict__ meta, int* __restrict__ tcnt, int* __restrict__ tcur,
                       int N){
    const long T0 = (long)N * D_DIM;
    const long T1 = T0 + (long)RNUM * D_DIM * TWO_D;
    const long T2 = T1 + (long)HC * D_DIM;
    const long T3 = T2 + (long)HC * D_DIM;
    const long stride = (long)gridDim.x * blockDim.x;
    const long gid = (long)blockIdx.x * blockDim.x + threadIdx.x;

    for (long i = gid; i < N; i += stride){ tcnt[i] = 0; tcur[i] = 0; }
    if (gid < RNUM) meta[M_CNT + gid] = 0;

    const long NE8 = T0 / 8;
    for (long i = gid; i < NE8; i += stride){
        const float4* p = (const float4*)(embs + i * 8);
        float4 a = p[0], b = p[1];
        us8 o;
        o[0]=f2bf(a.x); o[1]=f2bf(a.y); o[2]=f2bf(a.z); o[3]=f2bf(a.w);
        o[4]=f2bf(b.x); o[5]=f2bf(b.y); o[6]=f2bf(b.z); o[7]=f2bf(b.w);
        *(us8*)(embs_bf + i * 8) = o;
    }
    for (long i = T0 + gid; i < T3; i += stride){
        if (i < T1){
            long j = i - T0;
            int r = (int)(j >> 15);
            int rem = (int)(j & 32767);
            int n = rem >> 8, k = rem & 255;
            rel_t[j] = f2bf(rel[(long)r * 32768 + (long)k * D_DIM + n]);
        } else if (i < T2){
            long j = i - T1;
            int n = (int)(j >> 7), k = (int)(j & 127);
            W_e_t[j] = f2bf(W_e[(long)k * HC + n]);
        } else {
            long j = i - T2;
            int n = (int)(j >> 7), k = (int)(j & 127);
            W_l_t[j] = f2bf(W_l[(long)k * HC + n]);
        }
    }
}

// ---------------- counting: relation histogram + per-target degree (merged) ----------------
__global__ void k_count(const int* __restrict__ etype, const int* __restrict__ trg,
                        int* __restrict__ meta, int* __restrict__ tcnt, int E){
    __shared__ int h[RNUM];
    int tid = threadIdx.x;
    if (tid < RNUM) h[tid] = 0;
    __syncthreads();
    int e = blockIdx.x * 256 + tid;
    if (e < E){
        atomicAdd(&h[etype[e]], 1);
        atomicAdd(&tcnt[trg[e]], 1);
    }
    __syncthreads();
    if (tid < RNUM) atomicAdd(&meta[M_CNT + tid], h[tid]);
}

// ---------------- scatter: build CSR-ordered srcp/trgp/etypep ----------------
__global__ void k_scatter2(const int* __restrict__ etype, const int* __restrict__ trg,
                           const int* __restrict__ src,
                           const int* __restrict__ rowptr, int* __restrict__ tcur,
                           int* __restrict__ srcp, int* __restrict__ trgp,
                           int* __restrict__ etypep, int E){
    int e = blockIdx.x * 256 + threadIdx.x;
    if (e < E){
        int t = trg[e];
        int pos = rowptr[t] + atomicAdd(&tcur[t], 1);
        srcp[pos] = src[e];
        trgp[pos] = t;
        etypep[pos] = etype[e];
    }
}

// ---------------- rscatter: bucket CSR POSITIONS by relation (ascending within relation) ----------------
__global__ void k_rscatter(const int* __restrict__ etypep, int* __restrict__ meta,
                           int* __restrict__ perm, int E){
    __shared__ int lcnt[RNUM], lbase[RNUM];
    int tid = threadIdx.x;
    if (tid < RNUM) lcnt[tid] = 0;
    __syncthreads();
    int p = blockIdx.x * 256 + tid;
    int r = 0, rank = 0;
    if (p < E){ r = etypep[p]; rank = atomicAdd(&lcnt[r], 1); }
    __syncthreads();
    if (tid < RNUM) lbase[tid] = atomicAdd(&meta[M_CUR2 + tid], lcnt[tid]);
    __syncthreads();
    if (p < E) perm[meta[M_OFF + r] + lbase[r] + rank] = p;
}

// =================== MFMA GEMM kernels ===================
#define ZP 132

// ---------------- fat kernel: k_x blocks (staged A+B, round-11 body) + one tscan block ----------------
__global__ __launch_bounds__(256, 4) void k_x_tscan(
    const unsigned short* __restrict__ embs_bf, const unsigned short* __restrict__ W_l_t,
    const float* __restrict__ b_l, unsigned short* __restrict__ x_bf, int N,
    const int* __restrict__ tcnt, int* __restrict__ rowptr, int* __restrict__ meta)
{
    __shared__ __align__(16) char smem[64 * ZP * 4];

    // ---- last block: 256-thread scan (runs concurrently with the GEMM blocks) ----
    if (blockIdx.x == gridDim.x - 1){
        int* part = (int*)smem;
        const int T = 256;
        int tid = threadIdx.x;
        if (tid == 0){
            int offv = 0, blkv = 0;
            meta[M_OFF] = 0; meta[M_BLK] = 0;
            for (int r2 = 0; r2 < RNUM; r2++){
                int c = meta[M_CNT + r2];
                offv += c; blkv += (c + BM - 1) / BM;
                meta[M_OFF + r2 + 1] = offv;
                meta[M_BLK + r2 + 1] = blkv;
                meta[M_CUR + r2] = 0;
                meta[M_CUR2 + r2] = 0;
            }
        }
        int chunk = (N + T - 1) / T;
        int lo = tid * chunk, hi = min(lo + chunk, N);
        int s = 0;
        for (int i = lo; i < hi; i++) s += tcnt[i];
        part[tid] = s;
        __syncthreads();
        for (int off = 1; off < T; off <<= 1){
            int v = (tid >= off) ? part[tid - off] : 0;
            __syncthreads();
            part[tid] += v;
            __syncthreads();
        }
        int run = (tid == 0) ? 0 : part[tid - 1];
        for (int i = lo; i < hi; i++){ rowptr[i] = run; run += tcnt[i]; }
        if (tid == T - 1) rowptr[N] = part[T - 1];
        return;
    }

    unsigned short* Ab = (unsigned short*)smem;
    unsigned short* Bb = (unsigned short*)(smem + 16384);
    float* zb = (float*)smem;

    const int xb = (N + BM - 1) / BM;
    const int bid = blockIdx.x;
    const int cg = bid / xb;
    const int n0 = (bid - cg * xb) * BM;
    const int tid = threadIdx.x;
    const int cnt = min(BM, N - n0);
    const int w = tid >> 6, lane = tid & 63, m = lane & 15, q = lane >> 4;

    v4f acc[2][8];
    #pragma unroll
    for (int i = 0; i < 2; i++)
        #pragma unroll
        for (int j = 0; j < 8; j++) acc[i][j] = 0.f;

    #pragma unroll
    for (int ch = 0; ch < 2; ch++){
        __syncthreads();
        stage_gl(Ab, [&](int rr){ return embs_bf + (long)min(n0 + rr, N - 1) * D_DIM; },
                 ch * 64, tid);
        stage_gl(Bb, [&](int rr){ return W_l_t + (long)(cg * BM + rr) * D_DIM; },
                 ch * 64, tid);
        __syncthreads();
        #pragma unroll
        for (int ks = 0; ks < 2; ks++){
            v8s af[2], bf[8];
            #pragma unroll
            for (int rt = 0; rt < 2; rt++) af[rt] = frag_ld(Ab, w*32 + rt*16 + m, ks*4 + q);
            #pragma unroll
            for (int ct = 0; ct < 8; ct++) bf[ct] = frag_ld(Bb, ct*16 + m, ks*4 + q);
            #pragma unroll
            for (int rt = 0; rt < 2; rt++)
                #pragma unroll
                for (int ct = 0; ct < 8; ct++)
                    acc[rt][ct] = MFMA(af[rt], bf[ct], acc[rt][ct]);
        }
    }
    __syncthreads();

    for (int pp = 0; pp < 2; pp++){
        if ((w >> 1) == pp){
            int wr = (w & 1) * 32;
            #pragma unroll
            for (int rt = 0; rt < 2; rt++)
                #pragma unroll
                for (int ct = 0; ct < 8; ct++)
                    #pragma unroll
                    for (int g = 0; g < 4; g++)
                        zb[(wr + rt*16 + q*4 + g) * ZP + ct*16 + m] = acc[rt][ct][g];
        }
        __syncthreads();
        int rl = tid >> 2, pq = tid & 3;
        int row = pp * 64 + rl;
        if (row < cnt){
            const float* zp = zb + rl * ZP + pq * 32;
            const float* blp = b_l + cg * BM + pq * 32;
            long dst = (long)(n0 + row) * HC + cg * BM + pq * 32;
            #pragma unroll
            for (int g2 = 0; g2 < 4; g2++){
                us8 o;
                #pragma unroll
                for (int j = 0; j < 8; j++)
                    o[j] = f2bf(zp[g2*8 + j] + blp[g2*8 + j]);
                *(us8*)&x_bf[dst + g2*8] = o;
            }
        }
        __syncthreads();
    }
}

// ---------------- k_attr: relation-grouped over CSR positions; staged A+B (round-11 body) ----------------
__global__ __launch_bounds__(256, 4) void k_attr_mfma(
    const unsigned short* __restrict__ embs_bf, const int* __restrict__ srcp,
    const int* __restrict__ trgp, const unsigned short* __restrict__ rel_t,
    const int* __restrict__ perm, const int* __restrict__ meta,
    unsigned short* __restrict__ edge_attrp)
{
    __shared__ __align__(16) char smem[64 * ZP * 4];
    unsigned short* Ab = (unsigned short*)smem;
    unsigned short* Bb = (unsigned short*)(smem + 16384);
    float* zb = (float*)smem;
    __shared__ int s_ep[BM], s_s[BM], s_t[BM];
    __shared__ int s_meta[3];

    const int tid = threadIdx.x;
    const int b = blockIdx.x;
    if (tid == 0){
        int nblk = meta[M_BLK + RNUM];
        if (b >= nblk){ s_meta[0] = -1; }
        else {
            int r = 0;
            while (b >= meta[M_BLK + r + 1]) r++;
            int chunk = b - meta[M_BLK + r];
            int base = meta[M_OFF + r] + chunk * BM;
            s_meta[0] = r; s_meta[1] = base;
            s_meta[2] = min(BM, meta[M_OFF + r + 1] - base);
        }
    }
    __syncthreads();
    const int r = s_meta[0];
    if (r < 0) return;
    const int base = s_meta[1], cnt = s_meta[2];
    if (tid < BM){
        int pos = perm[base + min(tid, cnt - 1)];
        s_ep[tid] = pos; s_s[tid] = srcp[pos]; s_t[tid] = trgp[pos];
    }
    const int w = tid >> 6, lane = tid & 63, m = lane & 15, q = lane >> 4;

    v4f acc[2][8];
    #pragma unroll
    for (int i = 0; i < 2; i++)
        #pragma unroll
        for (int j = 0; j < 8; j++) acc[i][j] = 0.f;

    __syncthreads();

    #pragma unroll
    for (int ch = 0; ch < 4; ch++){
        __syncthreads();
        stage_gl(Ab, [&](int rr){ int node = (ch < 2) ? s_s[rr] : s_t[rr];
                                  return embs_bf + (long)node * D_DIM; },
                 (ch & 1) * 64, tid);
        stage_gl(Bb, [&](int rr){ return rel_t + ((long)r * BM + rr) * TWO_D; },
                 ch * 64, tid);
        __syncthreads();
        #pragma unroll
        for (int ks = 0; ks < 2; ks++){
            v8s af[2], bf[8];
            #pragma unroll
            for (int rt = 0; rt < 2; rt++) af[rt] = frag_ld(Ab, w*32 + rt*16 + m, ks*4 + q);
            #pragma unroll
            for (int ct = 0; ct < 8; ct++) bf[ct] = frag_ld(Bb, ct*16 + m, ks*4 + q);
            #pragma unroll
            for (int rt = 0; rt < 2; rt++)
                #pragma unroll
                for (int ct = 0; ct < 8; ct++)
                    acc[rt][ct] = MFMA(af[rt], bf[ct], acc[rt][ct]);
        }
    }
    __syncthreads();

    for (int pp = 0; pp < 2; pp++){
        if ((w >> 1) == pp){
            int wr = (w & 1) * 32;
            #pragma unroll
            for (int rt = 0; rt < 2; rt++)
                #pragma unroll
                for (int ct = 0; ct < 8; ct++)
                    #pragma unroll
                    for (int g = 0; g < 4; g++)
                        zb[(wr + rt*16 + q*4 + g) * ZP + ct*16 + m] = acc[rt][ct][g];
        }
        __syncthreads();
        int rl = tid >> 2, pq = tid & 3;
        int row = pp * 64 + rl;
        if (row < cnt){
            const float* zp = zb + rl * ZP + pq * 32;
            long dst = (long)s_ep[row] * D_DIM + pq * 32;
            #pragma unroll
            for (int g2 = 0; g2 < 4; g2++){
                us8 o;
                #pragma unroll
                for (int j = 0; j < 8; j++){
                    float v = zp[g2*8 + j];
                    v = 0.5f * v * (1.f + erff(v * 0.70710678118654752f));
                    o[j] = f2bf(v);
                }
                *(us8*)&edge_attrp[dst + g2*8] = o;
            }
        }
        __syncthreads();
    }
}

// ---------------- k_logits: XCD head-sibling dispatch; staged A+B (round-11 body) ----------------
__global__ __launch_bounds__(256, 4) void k_logits_mfma(
    const unsigned short* __restrict__ edge_attrp, const unsigned short* __restrict__ W_e_t,
    const float* __restrict__ att, const unsigned short* __restrict__ x_bf,
    const int* __restrict__ srcp, const int* __restrict__ trgp,
    float* __restrict__ logitsp, int E)
{
    __shared__ __align__(16) char smem[64 * ZP * 4];
    unsigned short* Ab = (unsigned short*)smem;
    unsigned short* Bb = (unsigned short*)(smem + 16384);
    float* zb = (float*)smem;
    __shared__ int s_s[BM], s_t[BM];

    const int tid = threadIdx.x;
    const int bid = blockIdx.x;
    const int g = bid >> 5, r5 = bid & 31;
    const int tile = g * 8 + (r5 & 7);
    const int h = r5 >> 3;
    const int lbv = (E + BM - 1) / BM;
    if (tile >= lbv) return;
    const int e0 = tile * BM;
    const int cnt = min(BM, E - e0);
    if (tid < BM){
        int e = e0 + min(tid, cnt - 1);
        s_s[tid] = srcp[e]; s_t[tid] = trgp[e];
    }
    const int w = tid >> 6, lane = tid & 63, m = lane & 15, q = lane >> 4;

    v4f acc[2][8];
    #pragma unroll
    for (int i = 0; i < 2; i++)
        #pragma unroll
        for (int j = 0; j < 8; j++) acc[i][j] = 0.f;

    #pragma unroll
    for (int ch = 0; ch < 2; ch++){
        __syncthreads();
        stage_gl(Ab, [&](int rr){ return edge_attrp + (long)(e0 + min(rr, cnt - 1)) * D_DIM; },
                 ch * 64, tid);
        stage_gl(Bb, [&](int rr){ return W_e_t + (long)(h * BM + rr) * D_DIM; },
                 ch * 64, tid);
        __syncthreads();
        #pragma unroll
        for (int ks = 0; ks < 2; ks++){
            v8s af[2], bf[8];
            #pragma unroll
            for (int rt = 0; rt < 2; rt++) af[rt] = frag_ld(Ab, w*32 + rt*16 + m, ks*4 + q);
            #pragma unroll
            for (int ct = 0; ct < 8; ct++) bf[ct] = frag_ld(Bb, ct*16 + m, ks*4 + q);
            #pragma unroll
            for (int rt = 0; rt < 2; rt++)
                #pragma unroll
                for (int ct = 0; ct < 8; ct++)
                    acc[rt][ct] = MFMA(af[rt], bf[ct], acc[rt][ct]);
        }
    }
    __syncthreads();

    for (int pp = 0; pp < 2; pp++){
        if ((w >> 1) == pp){
            int wr = (w & 1) * 32;
            #pragma unroll
            for (int rt = 0; rt < 2; rt++)
                #pragma unroll
                for (int ct = 0; ct < 8; ct++)
                    #pragma unroll
                    for (int g2 = 0; g2 < 4; g2++)
                        zb[(wr + rt*16 + q*4 + g2) * ZP + ct*16 + m] = acc[rt][ct][g2];
        }
        __syncthreads();
        int rl = tid >> 2, pq = tid & 3;
        int row = pp * 64 + rl;
        float part = 0.f;
        if (row < cnt){
            int s = s_s[row], t = s_t[row];
            const float* zp = zb + rl * ZP + pq * 32;
            const unsigned short* xip = x_bf + (long)t * HC + h * BM + pq * 32;
            const unsigned short* xjp = x_bf + (long)s * HC + h * BM + pq * 32;
            const float* ap = att + h * BM + pq * 32;
            #pragma unroll
            for (int g2 = 0; g2 < 4; g2++){
                us8 xi = *(const us8*)(xip + g2*8);
                us8 xj = *(const us8*)(xjp + g2*8);
                #pragma unroll
                for (int j = 0; j < 8; j++){
                    float z = zp[g2*8 + j] + bf2f(xi[j]) + bf2f(xj[j]);
                    z = (z > 0.f) ? z : 0.2f * z;
                    part += z * ap[g2*8 + j];
                }
            }
        }
        part += __shfl_xor(part, 1, 64);
        part += __shfl_xor(part, 2, 64);
        if ((tid & 3) == 0 && row < cnt)
            logitsp[(long)(e0 + row) * NH + h] = part;
        __syncthreads();
    }
}

// ---------------- CSR aggregation: contiguous logits/src, 2-pass softmax ----------------
__global__ __launch_bounds__(256) void k_agg_csr(
    const float* __restrict__ logitsp, const int* __restrict__ rowptr,
    const int* __restrict__ srcp,
    const unsigned short* __restrict__ x_bf, const float* __restrict__ bias,
    float* __restrict__ out, int N)
{
    int t = blockIdx.x * 4 + (threadIdx.x >> 6);
    if (t >= N) return;
    int lane = threadIdx.x & 63;
    int c0 = lane * 8;
    int h = lane >> 4;                   // head for my 8 cols
    int lo = rowptr[t], hi = rowptr[t + 1];

    float acc[8];
    #pragma unroll
    for (int j = 0; j < 8; j++) acc[j] = 0.f;

    if (lo < hi){
        float mx = -3.0e38f;
        for (int i = lo; i < hi; i++)
            mx = fmaxf(mx, logitsp[(long)i * NH + h]);
        float ssum = 0.f;
        for (int i = lo; i < hi; i++){
            float ew = expf(logitsp[(long)i * NH + h] - mx);
            ssum += ew;
            us8 xv = *(const us8*)&x_bf[(long)srcp[i] * HC + c0];
            #pragma unroll
            for (int j = 0; j < 8; j++) acc[j] += ew * bf2f(xv[j]);
        }
        float inv = 1.f / fmaxf(ssum, 1e-16f);
        #pragma unroll
        for (int j = 0; j < 8; j++) acc[j] *= inv;
    }
    long dst = (long)t * HC + c0;
    *(float4*)&out[dst]     = make_float4(acc[0] + bias[c0+0], acc[1] + bias[c0+1],
                                          acc[2] + bias[c0+2], acc[3] + bias[c0+3]);
    *(float4*)&out[dst + 4] = make_float4(acc[4] + bias[c0+4], acc[5] + bias[c0+5],
                                          acc[6] + bias[c0+6], acc[7] + bias[c0+7]);
}

extern "C" void kernel_launch(void* const* d_in, const int* in_sizes, int n_in,
                              void* d_out, int out_size, void* d_ws, size_t ws_size,
                              hipStream_t stream) {
    const float* embs       = (const float*)d_in[0];
    const int*   edge_index = (const int*)  d_in[1];
    const int*   etype      = (const int*)  d_in[2];
    const float* rel        = (const float*)d_in[3];
    const float* W_l        = (const float*)d_in[4];
    const float* b_l        = (const float*)d_in[5];
    const float* W_e        = (const float*)d_in[6];
    const float* att        = (const float*)d_in[7];
    const float* bias       = (const float*)d_in[8];

    const int N = in_sizes[0] / D_DIM;
    const int E = in_sizes[1] / 2;
    const int* src = edge_index;
    const int* trg = edge_index + E;

    char* ws = (char*)d_ws;
    size_t off = 0;
    unsigned short* x_bf = (unsigned short*)(ws + off);      off += (size_t)N * HC * 2;
    unsigned short* embs_bf = (unsigned short*)(ws + off);   off += (size_t)N * D_DIM * 2;
    unsigned short* edge_attrp = (unsigned short*)(ws + off); off += (size_t)E * D_DIM * 2;
    unsigned short* rel_t = (unsigned short*)(ws + off);     off += (size_t)RNUM * D_DIM * TWO_D * 2;
    unsigned short* W_e_t = (unsigned short*)(ws + off);     off += (size_t)HC * D_DIM * 2;
    unsigned short* W_l_t = (unsigned short*)(ws + off);     off += (size_t)HC * D_DIM * 2;
    float* logitsp = (float*)(ws + off);                     off += (size_t)E * NH * 4;
    int* perm = (int*)(ws + off);                            off += (size_t)E * 4;
    int* meta = (int*)(ws + off);                            off += 64 * 4;
    int* tcnt = (int*)(ws + off);                            off += (size_t)N * 4;
    int* tcur = (int*)(ws + off);                            off += (size_t)N * 4;
    int* rowptr = (int*)(ws + off);                          off += (size_t)(N + 1) * 4;
    int* etypep = (int*)(ws + off);                          off += (size_t)E * 4;
    int* srcp = (int*)(ws + off);                            off += (size_t)E * 4;
    int* trgp = (int*)(ws + off);                            off += (size_t)E * 4;

    float* out = (float*)d_out;

    const int eb = (E + 255) / 256;
    const int ab = (E + BM - 1) / BM + RNUM;
    const int lb = (E + BM - 1) / BM;
    const int xb = (N + BM - 1) / BM;
    const int lgrid = ((lb + 7) / 8) * 32;   // tile-octet groups x 4 heads

    k_prep<<<2048, 256, 0, stream>>>(embs, rel, W_e, W_l, embs_bf, rel_t, W_e_t, W_l_t,
                                     meta, tcnt, tcur, N);
    k_count<<<eb, 256, 0, stream>>>(etype, trg, meta, tcnt, E);
    k_x_tscan<<<xb * NH + 1, 256, 0, stream>>>(embs_bf, W_l_t, b_l, x_bf, N,
                                               tcnt, rowptr, meta);
    k_scatter2<<<eb, 256, 0, stream>>>(etype, trg, src, rowptr, tcur, srcp, trgp, etypep, E);
    k_rscatter<<<eb, 256, 0, stream>>>(etypep, meta, perm, E);
    k_attr_mfma<<<ab, 256, 0, stream>>>(embs_bf, srcp, trgp, rel_t, perm, meta, edge_attrp);
    k_logits_mfma<<<lgrid, 256, 0, stream>>>(edge_attrp, W_e_t, att, x_bf, srcp, trgp,
                                             logitsp, E);
    k_agg_csr<<<(N + 3) / 4, 256, 0, stream>>>(logitsp, rowptr, srcp, x_bf, bias, out, N);
}

// Round 14
// 397.870 us; speedup vs baseline: 1.5623x; 1.1777x over previous
//
#include <hip/hip_runtime.h>
#include <math.h>

#define D_DIM 128
#define TWO_D 256
#define HC    512
#define NH    4
#define RNUM  8
#define BM    128

#define M_CNT  0
#define M_OFF  8
#define M_BLK  17
#define M_CUR  26
#define M_CUR2 34

typedef __attribute__((ext_vector_type(8))) short v8s;
typedef __attribute__((ext_vector_type(4))) float v4f;
typedef __attribute__((ext_vector_type(8))) unsigned short us8;

#define MFMA(a,b,c) __builtin_amdgcn_mfma_f32_16x16x32_bf16((a),(b),(c),0,0,0)

__device__ __forceinline__ float bf2f(unsigned short v){
    return __uint_as_float(((unsigned)v) << 16);
}
__device__ __forceinline__ unsigned short f2bf(float f){
    unsigned u = __float_as_uint(f);
    u += 0x7fffu + ((u >> 16) & 1u);
    return (unsigned short)(u >> 16);
}

// ---- LDS swizzled tile: slot cp of row r holds global chunk cp^(r&7) ----
__device__ __forceinline__ v8s frag_ld(const unsigned short* buf, int r, int chunk){
    return *(const v8s*)(buf + r * 64 + ((chunk ^ (r & 7)) << 3));
}

// ---- async staging: global_load_lds width=16, linear LDS dest + swizzled SOURCE (rule #21) ----
template<typename RowFn>
__device__ __forceinline__ void stage_gl(unsigned short* lds, RowFn rowp, int col0, int tid){
    const int lane = tid & 63;
    const int w = tid >> 6;
    #pragma unroll
    for (int i = 0; i < 4; i++){
        const int k = w * 4 + i;
        const int o = k * 1024 + lane * 16;     // byte offset within tile
        const int rr = o >> 7;                  // row (128 B/row)
        const int cp = (o & 127) >> 4;          // LDS chunk slot
        const int cg = cp ^ (rr & 7);           // global chunk (source pre-swizzle)
        const unsigned short* src = rowp(rr) + col0 + cg * 8;
        unsigned short* dst = lds + k * 512;    // wave-uniform base (elems)
        __builtin_amdgcn_global_load_lds((const __attribute__((address_space(1))) void*)src,
                                         (__attribute__((address_space(3))) void*)dst,
                                         16, 0, 0);
    }
}

// ---------------- prep: bf16 conversions + transposes + counter init (merged) ----------------
__global__ void k_prep(const float* __restrict__ embs, const float* __restrict__ rel,
                       const float* __restrict__ W_e, const float* __restrict__ W_l,
                       unsigned short* __restrict__ embs_bf, unsigned short* __restrict__ rel_t,
                       unsigned short* __restrict__ W_e_t, unsigned short* __restrict__ W_l_t,
                       int* __restrict__ meta, int* __restrict__ tcnt, int* __restrict__ tcur,
                       int N){
    const long T0 = (long)N * D_DIM;
    const long T1 = T0 + (long)RNUM * D_DIM * TWO_D;
    const long T2 = T1 + (long)HC * D_DIM;
    const long T3 = T2 + (long)HC * D_DIM;
    const long stride = (long)gridDim.x * blockDim.x;
    const long gid = (long)blockIdx.x * blockDim.x + threadIdx.x;

    for (long i = gid; i < N; i += stride){ tcnt[i] = 0; tcur[i] = 0; }
    if (gid < RNUM) meta[M_CNT + gid] = 0;

    const long NE8 = T0 / 8;
    for (long i = gid; i < NE8; i += stride){
        const float4* p = (const float4*)(embs + i * 8);
        float4 a = p[0], b = p[1];
        us8 o;
        o[0]=f2bf(a.x); o[1]=f2bf(a.y); o[2]=f2bf(a.z); o[3]=f2bf(a.w);
        o[4]=f2bf(b.x); o[5]=f2bf(b.y); o[6]=f2bf(b.z); o[7]=f2bf(b.w);
        *(us8*)(embs_bf + i * 8) = o;
    }
    for (long i = T0 + gid; i < T3; i += stride){
        if (i < T1){
            long j = i - T0;
            int r = (int)(j >> 15);
            int rem = (int)(j & 32767);
            int n = rem >> 8, k = rem & 255;
            rel_t[j] = f2bf(rel[(long)r * 32768 + (long)k * D_DIM + n]);
        } else if (i < T2){
            long j = i - T1;
            int n = (int)(j >> 7), k = (int)(j & 127);
            W_e_t[j] = f2bf(W_e[(long)k * HC + n]);
        } else {
            long j = i - T2;
            int n = (int)(j >> 7), k = (int)(j & 127);
            W_l_t[j] = f2bf(W_l[(long)k * HC + n]);
        }
    }
}

// ---------------- counting: relation histogram + per-target degree (merged) ----------------
__global__ void k_count(const int* __restrict__ etype, const int* __restrict__ trg,
                        int* __restrict__ meta, int* __restrict__ tcnt, int E){
    __shared__ int h[RNUM];
    int tid = threadIdx.x;
    if (tid < RNUM) h[tid] = 0;
    __syncthreads();
    int e = blockIdx.x * 256 + tid;
    if (e < E){
        atomicAdd(&h[etype[e]], 1);
        atomicAdd(&tcnt[trg[e]], 1);
    }
    __syncthreads();
    if (tid < RNUM) atomicAdd(&meta[M_CNT + tid], h[tid]);
}

// ---------------- bsum: per-256-chunk sums of tcnt (parallel, coalesced) + meta offsets ----------------
__global__ __launch_bounds__(256) void k_bsum(const int* __restrict__ tcnt,
                                              int* __restrict__ bsum,
                                              int* __restrict__ meta, int N){
    __shared__ int red[256];
    int tid = threadIdx.x;
    int i = blockIdx.x * 256 + tid;
    red[tid] = (i < N) ? tcnt[i] : 0;
    __syncthreads();
    for (int off = 128; off > 0; off >>= 1){
        if (tid < off) red[tid] += red[tid + off];
        __syncthreads();
    }
    if (tid == 0) bsum[blockIdx.x] = red[0];
    if (blockIdx.x == 0 && tid == 0){
        int offv = 0, blkv = 0;
        meta[M_OFF] = 0; meta[M_BLK] = 0;
        for (int r2 = 0; r2 < RNUM; r2++){
            int c = meta[M_CNT + r2];
            offv += c; blkv += (c + BM - 1) / BM;
            meta[M_OFF + r2 + 1] = offv;
            meta[M_BLK + r2 + 1] = blkv;
            meta[M_CUR + r2] = 0;
            meta[M_CUR2 + r2] = 0;
        }
    }
}

// ---------------- cscan: per-chunk exclusive scan + chunk offset -> rowptr (parallel) ----------------
__global__ __launch_bounds__(256) void k_cscan(const int* __restrict__ tcnt,
                                               const int* __restrict__ bsum,
                                               int* __restrict__ rowptr, int N, int NB){
    __shared__ int pre[256];
    __shared__ int sOff;
    int tid = threadIdx.x;
    int b = blockIdx.x;

    // offset = sum of bsum[0..b)
    int s = 0;
    for (int j = tid; j < b; j += 256) s += bsum[j];
    pre[tid] = s;
    __syncthreads();
    for (int off = 128; off > 0; off >>= 1){
        if (tid < off) pre[tid] += pre[tid + off];
        __syncthreads();
    }
    if (tid == 0) sOff = pre[0];
    __syncthreads();
    const int base = sOff;
    __syncthreads();

    // chunk-local inclusive scan (Hillis-Steele in LDS)
    int i = b * 256 + tid;
    int v = (i < N) ? tcnt[i] : 0;
    pre[tid] = v;
    __syncthreads();
    for (int off = 1; off < 256; off <<= 1){
        int t = (tid >= off) ? pre[tid - off] : 0;
        __syncthreads();
        pre[tid] += t;
        __syncthreads();
    }
    if (i < N) rowptr[i] = base + pre[tid] - v;       // exclusive prefix
    if (i == N) rowptr[N] = base + pre[tid];          // total (v==0 here)
    if (b == NB - 1 && (b + 1) * 256 == N && tid == 255)
        rowptr[N] = base + pre[255];                  // N multiple of 256 fallback
}

// ---------------- scatter: build CSR-ordered srcp/trgp/etypep ----------------
__global__ void k_scatter2(const int* __restrict__ etype, const int* __restrict__ trg,
                           const int* __restrict__ src,
                           const int* __restrict__ rowptr, int* __restrict__ tcur,
                           int* __restrict__ srcp, int* __restrict__ trgp,
                           int* __restrict__ etypep, int E){
    int e = blockIdx.x * 256 + threadIdx.x;
    if (e < E){
        int t = trg[e];
        int pos = rowptr[t] + atomicAdd(&tcur[t], 1);
        srcp[pos] = src[e];
        trgp[pos] = t;
        etypep[pos] = etype[e];
    }
}

// ---------------- rscatter: bucket CSR POSITIONS by relation (ascending within relation) ----------------
__global__ void k_rscatter(const int* __restrict__ etypep, int* __restrict__ meta,
                           int* __restrict__ perm, int E){
    __shared__ int lcnt[RNUM], lbase[RNUM];
    int tid = threadIdx.x;
    if (tid < RNUM) lcnt[tid] = 0;
    __syncthreads();
    int p = blockIdx.x * 256 + tid;
    int r = 0, rank = 0;
    if (p < E){ r = etypep[p]; rank = atomicAdd(&lcnt[r], 1); }
    __syncthreads();
    if (tid < RNUM) lbase[tid] = atomicAdd(&meta[M_CUR2 + tid], lcnt[tid]);
    __syncthreads();
    if (p < E) perm[meta[M_OFF + r] + lbase[r] + rank] = p;
}

// =================== MFMA GEMM kernels ===================
#define ZP 132

// ---------------- k_x: x_bf = bf16(embs @ W_l + b_l), staged A+B (round-11 body) ----------------
__global__ __launch_bounds__(256, 4) void k_x_mfma(
    const unsigned short* __restrict__ embs_bf, const unsigned short* __restrict__ W_l_t,
    const float* __restrict__ b_l, unsigned short* __restrict__ x_bf, int N)
{
    __shared__ __align__(16) char smem[64 * ZP * 4];
    unsigned short* Ab = (unsigned short*)smem;
    unsigned short* Bb = (unsigned short*)(smem + 16384);
    float* zb = (float*)smem;

    const int tid = threadIdx.x;
    const int n0 = blockIdx.x * BM;
    const int cg = blockIdx.y;
    const int cnt = min(BM, N - n0);
    const int w = tid >> 6, lane = tid & 63, m = lane & 15, q = lane >> 4;

    v4f acc[2][8];
    #pragma unroll
    for (int i = 0; i < 2; i++)
        #pragma unroll
        for (int j = 0; j < 8; j++) acc[i][j] = 0.f;

    #pragma unroll
    for (int ch = 0; ch < 2; ch++){
        __syncthreads();
        stage_gl(Ab, [&](int rr){ return embs_bf + (long)min(n0 + rr, N - 1) * D_DIM; },
                 ch * 64, tid);
        stage_gl(Bb, [&](int rr){ return W_l_t + (long)(cg * BM + rr) * D_DIM; },
                 ch * 64, tid);
        __syncthreads();
        #pragma unroll
        for (int ks = 0; ks < 2; ks++){
            v8s af[2], bf[8];
            #pragma unroll
            for (int rt = 0; rt < 2; rt++) af[rt] = frag_ld(Ab, w*32 + rt*16 + m, ks*4 + q);
            #pragma unroll
            for (int ct = 0; ct < 8; ct++) bf[ct] = frag_ld(Bb, ct*16 + m, ks*4 + q);
            #pragma unroll
            for (int rt = 0; rt < 2; rt++)
                #pragma unroll
                for (int ct = 0; ct < 8; ct++)
                    acc[rt][ct] = MFMA(af[rt], bf[ct], acc[rt][ct]);
        }
    }
    __syncthreads();

    for (int pp = 0; pp < 2; pp++){
        if ((w >> 1) == pp){
            int wr = (w & 1) * 32;
            #pragma unroll
            for (int rt = 0; rt < 2; rt++)
                #pragma unroll
                for (int ct = 0; ct < 8; ct++)
                    #pragma unroll
                    for (int g = 0; g < 4; g++)
                        zb[(wr + rt*16 + q*4 + g) * ZP + ct*16 + m] = acc[rt][ct][g];
        }
        __syncthreads();
        int rl = tid >> 2, pq = tid & 3;
        int row = pp * 64 + rl;
        if (row < cnt){
            const float* zp = zb + rl * ZP + pq * 32;
            const float* blp = b_l + cg * BM + pq * 32;
            long dst = (long)(n0 + row) * HC + cg * BM + pq * 32;
            #pragma unroll
            for (int g2 = 0; g2 < 4; g2++){
                us8 o;
                #pragma unroll
                for (int j = 0; j < 8; j++)
                    o[j] = f2bf(zp[g2*8 + j] + blp[g2*8 + j]);
                *(us8*)&x_bf[dst + g2*8] = o;
            }
        }
        __syncthreads();
    }
}

// ---------------- k_attr: relation-grouped over CSR positions; staged A+B ----------------
__global__ __launch_bounds__(256, 4) void k_attr_mfma(
    const unsigned short* __restrict__ embs_bf, const int* __restrict__ srcp,
    const int* __restrict__ trgp, const unsigned short* __restrict__ rel_t,
    const int* __restrict__ perm, const int* __restrict__ meta,
    unsigned short* __restrict__ edge_attrp)
{
    __shared__ __align__(16) char smem[64 * ZP * 4];
    unsigned short* Ab = (unsigned short*)smem;
    unsigned short* Bb = (unsigned short*)(smem + 16384);
    float* zb = (float*)smem;
    __shared__ int s_ep[BM], s_s[BM], s_t[BM];
    __shared__ int s_meta[3];

    const int tid = threadIdx.x;
    const int b = blockIdx.x;
    if (tid == 0){
        int nblk = meta[M_BLK + RNUM];
        if (b >= nblk){ s_meta[0] = -1; }
        else {
            int r = 0;
            while (b >= meta[M_BLK + r + 1]) r++;
            int chunk = b - meta[M_BLK + r];
            int base = meta[M_OFF + r] + chunk * BM;
            s_meta[0] = r; s_meta[1] = base;
            s_meta[2] = min(BM, meta[M_OFF + r + 1] - base);
        }
    }
    __syncthreads();
    const int r = s_meta[0];
    if (r < 0) return;
    const int base = s_meta[1], cnt = s_meta[2];
    if (tid < BM){
        int pos = perm[base + min(tid, cnt - 1)];
        s_ep[tid] = pos; s_s[tid] = srcp[pos]; s_t[tid] = trgp[pos];
    }
    const int w = tid >> 6, lane = tid & 63, m = lane & 15, q = lane >> 4;

    v4f acc[2][8];
    #pragma unroll
    for (int i = 0; i < 2; i++)
        #pragma unroll
        for (int j = 0; j < 8; j++) acc[i][j] = 0.f;

    __syncthreads();

    #pragma unroll
    for (int ch = 0; ch < 4; ch++){
        __syncthreads();
        stage_gl(Ab, [&](int rr){ int node = (ch < 2) ? s_s[rr] : s_t[rr];
                                  return embs_bf + (long)node * D_DIM; },
                 (ch & 1) * 64, tid);
        stage_gl(Bb, [&](int rr){ return rel_t + ((long)r * BM + rr) * TWO_D; },
                 ch * 64, tid);
        __syncthreads();
        #pragma unroll
        for (int ks = 0; ks < 2; ks++){
            v8s af[2], bf[8];
            #pragma unroll
            for (int rt = 0; rt < 2; rt++) af[rt] = frag_ld(Ab, w*32 + rt*16 + m, ks*4 + q);
            #pragma unroll
            for (int ct = 0; ct < 8; ct++) bf[ct] = frag_ld(Bb, ct*16 + m, ks*4 + q);
            #pragma unroll
            for (int rt = 0; rt < 2; rt++)
                #pragma unroll
                for (int ct = 0; ct < 8; ct++)
                    acc[rt][ct] = MFMA(af[rt], bf[ct], acc[rt][ct]);
        }
    }
    __syncthreads();

    for (int pp = 0; pp < 2; pp++){
        if ((w >> 1) == pp){
            int wr = (w & 1) * 32;
            #pragma unroll
            for (int rt = 0; rt < 2; rt++)
                #pragma unroll
                for (int ct = 0; ct < 8; ct++)
                    #pragma unroll
                    for (int g = 0; g < 4; g++)
                        zb[(wr + rt*16 + q*4 + g) * ZP + ct*16 + m] = acc[rt][ct][g];
        }
        __syncthreads();
        int rl = tid >> 2, pq = tid & 3;
        int row = pp * 64 + rl;
        if (row < cnt){
            const float* zp = zb + rl * ZP + pq * 32;
            long dst = (long)s_ep[row] * D_DIM + pq * 32;
            #pragma unroll
            for (int g2 = 0; g2 < 4; g2++){
                us8 o;
                #pragma unroll
                for (int j = 0; j < 8; j++){
                    float v = zp[g2*8 + j];
                    v = 0.5f * v * (1.f + erff(v * 0.70710678118654752f));
                    o[j] = f2bf(v);
                }
                *(us8*)&edge_attrp[dst + g2*8] = o;
            }
        }
        __syncthreads();
    }
}

// ---------------- k_logits: XCD head-sibling dispatch; staged A+B ----------------
__global__ __launch_bounds__(256, 4) void k_logits_mfma(
    const unsigned short* __restrict__ edge_attrp, const unsigned short* __restrict__ W_e_t,
    const float* __restrict__ att, const unsigned short* __restrict__ x_bf,
    const int* __restrict__ srcp, const int* __restrict__ trgp,
    float* __restrict__ logitsp, int E)
{
    __shared__ __align__(16) char smem[64 * ZP * 4];
    unsigned short* Ab = (unsigned short*)smem;
    unsigned short* Bb = (unsigned short*)(smem + 16384);
    float* zb = (float*)smem;
    __shared__ int s_s[BM], s_t[BM];

    const int tid = threadIdx.x;
    const int bid = blockIdx.x;
    const int g = bid >> 5, r5 = bid & 31;
    const int tile = g * 8 + (r5 & 7);
    const int h = r5 >> 3;
    const int lbv = (E + BM - 1) / BM;
    if (tile >= lbv) return;
    const int e0 = tile * BM;
    const int cnt = min(BM, E - e0);
    if (tid < BM){
        int e = e0 + min(tid, cnt - 1);
        s_s[tid] = srcp[e]; s_t[tid] = trgp[e];
    }
    const int w = tid >> 6, lane = tid & 63, m = lane & 15, q = lane >> 4;

    v4f acc[2][8];
    #pragma unroll
    for (int i = 0; i < 2; i++)
        #pragma unroll
        for (int j = 0; j < 8; j++) acc[i][j] = 0.f;

    #pragma unroll
    for (int ch = 0; ch < 2; ch++){
        __syncthreads();
        stage_gl(Ab, [&](int rr){ return edge_attrp + (long)(e0 + min(rr, cnt - 1)) * D_DIM; },
                 ch * 64, tid);
        stage_gl(Bb, [&](int rr){ return W_e_t + (long)(h * BM + rr) * D_DIM; },
                 ch * 64, tid);
        __syncthreads();
        #pragma unroll
        for (int ks = 0; ks < 2; ks++){
            v8s af[2], bf[8];
            #pragma unroll
            for (int rt = 0; rt < 2; rt++) af[rt] = frag_ld(Ab, w*32 + rt*16 + m, ks*4 + q);
            #pragma unroll
            for (int ct = 0; ct < 8; ct++) bf[ct] = frag_ld(Bb, ct*16 + m, ks*4 + q);
            #pragma unroll
            for (int rt = 0; rt < 2; rt++)
                #pragma unroll
                for (int ct = 0; ct < 8; ct++)
                    acc[rt][ct] = MFMA(af[rt], bf[ct], acc[rt][ct]);
        }
    }
    __syncthreads();

    for (int pp = 0; pp < 2; pp++){
        if ((w >> 1) == pp){
            int wr = (w & 1) * 32;
            #pragma unroll
            for (int rt = 0; rt < 2; rt++)
                #pragma unroll
                for (int ct = 0; ct < 8; ct++)
                    #pragma unroll
                    for (int g2 = 0; g2 < 4; g2++)
                        zb[(wr + rt*16 + q*4 + g2) * ZP + ct*16 + m] = acc[rt][ct][g2];
        }
        __syncthreads();
        int rl = tid >> 2, pq = tid & 3;
        int row = pp * 64 + rl;
        float part = 0.f;
        if (row < cnt){
            int s = s_s[row], t = s_t[row];
            const float* zp = zb + rl * ZP + pq * 32;
            const unsigned short* xip = x_bf + (long)t * HC + h * BM + pq * 32;
            const unsigned short* xjp = x_bf + (long)s * HC + h * BM + pq * 32;
            const float* ap = att + h * BM + pq * 32;
            #pragma unroll
            for (int g2 = 0; g2 < 4; g2++){
                us8 xi = *(const us8*)(xip + g2*8);
                us8 xj = *(const us8*)(xjp + g2*8);
                #pragma unroll
                for (int j = 0; j < 8; j++){
                    float z = zp[g2*8 + j] + bf2f(xi[j]) + bf2f(xj[j]);
                    z = (z > 0.f) ? z : 0.2f * z;
                    part += z * ap[g2*8 + j];
                }
            }
        }
        part += __shfl_xor(part, 1, 64);
        part += __shfl_xor(part, 2, 64);
        if ((tid & 3) == 0 && row < cnt)
            logitsp[(long)(e0 + row) * NH + h] = part;
        __syncthreads();
    }
}

// ---------------- CSR aggregation: contiguous logits/src, 2-pass softmax ----------------
__global__ __launch_bounds__(256) void k_agg_csr(
    const float* __restrict__ logitsp, const int* __restrict__ rowptr,
    const int* __restrict__ srcp,
    const unsigned short* __restrict__ x_bf, const float* __restrict__ bias,
    float* __restrict__ out, int N)
{
    int t = blockIdx.x * 4 + (threadIdx.x >> 6);
    if (t >= N) return;
    int lane = threadIdx.x & 63;
    int c0 = lane * 8;
    int h = lane >> 4;                   // head for my 8 cols
    int lo = rowptr[t], hi = rowptr[t + 1];

    float acc[8];
    #pragma unroll
    for (int j = 0; j < 8; j++) acc[j] = 0.f;

    if (lo < hi){
        float mx = -3.0e38f;
        for (int i = lo; i < hi; i++)
            mx = fmaxf(mx, logitsp[(long)i * NH + h]);
        float ssum = 0.f;
        for (int i = lo; i < hi; i++){
            float ew = expf(logitsp[(long)i * NH + h] - mx);
            ssum += ew;
            us8 xv = *(const us8*)&x_bf[(long)srcp[i] * HC + c0];
            #pragma unroll
            for (int j = 0; j < 8; j++) acc[j] += ew * bf2f(xv[j]);
        }
        float inv = 1.f / fmaxf(ssum, 1e-16f);
        #pragma unroll
        for (int j = 0; j < 8; j++) acc[j] *= inv;
    }
    long dst = (long)t * HC + c0;
    *(float4*)&out[dst]     = make_float4(acc[0] + bias[c0+0], acc[1] + bias[c0+1],
                                          acc[2] + bias[c0+2], acc[3] + bias[c0+3]);
    *(float4*)&out[dst + 4] = make_float4(acc[4] + bias[c0+4], acc[5] + bias[c0+5],
                                          acc[6] + bias[c0+6], acc[7] + bias[c0+7]);
}

extern "C" void kernel_launch(void* const* d_in, const int* in_sizes, int n_in,
                              void* d_out, int out_size, void* d_ws, size_t ws_size,
                              hipStream_t stream) {
    const float* embs       = (const float*)d_in[0];
    const int*   edge_index = (const int*)  d_in[1];
    const int*   etype      = (const int*)  d_in[2];
    const float* rel        = (const float*)d_in[3];
    const float* W_l        = (const float*)d_in[4];
    const float* b_l        = (const float*)d_in[5];
    const float* W_e        = (const float*)d_in[6];
    const float* att        = (const float*)d_in[7];
    const float* bias       = (const float*)d_in[8];

    const int N = in_sizes[0] / D_DIM;
    const int E = in_sizes[1] / 2;
    const int* src = edge_index;
    const int* trg = edge_index + E;

    char* ws = (char*)d_ws;
    size_t off = 0;
    unsigned short* x_bf = (unsigned short*)(ws + off);      off += (size_t)N * HC * 2;
    unsigned short* embs_bf = (unsigned short*)(ws + off);   off += (size_t)N * D_DIM * 2;
    unsigned short* edge_attrp = (unsigned short*)(ws + off); off += (size_t)E * D_DIM * 2;
    unsigned short* rel_t = (unsigned short*)(ws + off);     off += (size_t)RNUM * D_DIM * TWO_D * 2;
    unsigned short* W_e_t = (unsigned short*)(ws + off);     off += (size_t)HC * D_DIM * 2;
    unsigned short* W_l_t = (unsigned short*)(ws + off);     off += (size_t)HC * D_DIM * 2;
    float* logitsp = (float*)(ws + off);                     off += (size_t)E * NH * 4;
    int* perm = (int*)(ws + off);                            off += (size_t)E * 4;
    int* meta = (int*)(ws + off);                            off += 64 * 4;
    int* tcnt = (int*)(ws + off);                            off += (size_t)N * 4;
    int* tcur = (int*)(ws + off);                            off += (size_t)N * 4;
    int* rowptr = (int*)(ws + off);                          off += (size_t)(N + 1) * 4;
    int* etypep = (int*)(ws + off);                          off += (size_t)E * 4;
    int* srcp = (int*)(ws + off);                            off += (size_t)E * 4;
    int* trgp = (int*)(ws + off);                            off += (size_t)E * 4;
    int* bsum = (int*)(ws + off);                            off += 1024 * 4;

    float* out = (float*)d_out;

    const int eb = (E + 255) / 256;
    const int nb = (N + 255) / 256;       // scan chunks
    const int ab = (E + BM - 1) / BM + RNUM;
    const int lb = (E + BM - 1) / BM;
    const int lgrid = ((lb + 7) / 8) * 32;   // tile-octet groups x 4 heads

    k_prep<<<2048, 256, 0, stream>>>(embs, rel, W_e, W_l, embs_bf, rel_t, W_e_t, W_l_t,
                                     meta, tcnt, tcur, N);
    k_count<<<eb, 256, 0, stream>>>(etype, trg, meta, tcnt, E);
    k_bsum<<<nb, 256, 0, stream>>>(tcnt, bsum, meta, N);
    k_cscan<<<nb, 256, 0, stream>>>(tcnt, bsum, rowptr, N, nb);
    k_scatter2<<<eb, 256, 0, stream>>>(etype, trg, src, rowptr, tcur, srcp, trgp, etypep, E);
    k_rscatter<<<eb, 256, 0, stream>>>(etypep, meta, perm, E);
    k_x_mfma<<<dim3((N + BM - 1) / BM, NH), 256, 0, stream>>>(embs_bf, W_l_t, b_l, x_bf, N);
    k_attr_mfma<<<ab, 256, 0, stream>>>(embs_bf, srcp, trgp, rel_t, perm, meta, edge_attrp);
    k_logits_mfma<<<lgrid, 256, 0, stream>>>(edge_attrp, W_e_t, att, x_bf, srcp, trgp,
                                             logitsp, E);
    k_agg_csr<<<(N + 3) / 4, 256, 0, stream>>>(logitsp, rowptr, srcp, x_bf, bias, out, N);
}